// Round 1
// baseline (255.734 us; speedup 1.0000x reference)
//
#include <hip/hip_runtime.h>
#include <hip/hip_bf16.h>

#define NUM_B 8
#define SEQ   1024
#define DIM   768
#define NH    12
#define HD    64

typedef __bf16 bf16x8 __attribute__((ext_vector_type(8)));
typedef float  f32x4  __attribute__((ext_vector_type(4)));

__device__ __forceinline__ unsigned short f2bf(float f) {
  unsigned int u = __float_as_uint(f);
  u += 0x7FFFu + ((u >> 16) & 1u);   // RNE
  return (unsigned short)(u >> 16);
}

// ---------- fp32 -> bf16, 4 elems/thread ----------
__global__ void cvt_kernel(const float* __restrict__ in, unsigned short* __restrict__ out, int n) {
  int i = (blockIdx.x * blockDim.x + threadIdx.x) * 4;
  if (i >= n) return;
  float4 v = *(const float4*)(in + i);
  ushort4 o = { f2bf(v.x), f2bf(v.y), f2bf(v.z), f2bf(v.w) };
  *(ushort4*)(out + i) = o;
}

// ---------- transpose+convert: in [R][C] f32 -> out [C][R] bf16 ----------
__global__ void tcvt_kernel(const float* __restrict__ in, unsigned short* __restrict__ out,
                            int R, int C) {
  __shared__ unsigned short tile[32][33];
  int c0 = blockIdx.x * 32, r0 = blockIdx.y * 32;
  int tx = threadIdx.x, ty = threadIdx.y;   // (32, 8)
  #pragma unroll
  for (int i = 0; i < 32; i += 8)
    tile[ty + i][tx] = f2bf(in[(size_t)(r0 + ty + i) * C + c0 + tx]);
  __syncthreads();
  #pragma unroll
  for (int i = 0; i < 32; i += 8)
    out[(size_t)(c0 + ty + i) * R + r0 + tx] = tile[tx][ty + i];
}

// ---------- 128x128 bf16 GEMM, A [M][K], Bt [N][K], 4 waves ----------
// QKV=true: scatter C into q [B,h,N,d], k [B,h,N,d], v^T [B,h,d,N] (all bf16)
// QKV=false: C = A*B + bias -> fp32 out [M][768]
template<bool QKV>
__global__ __launch_bounds__(256) void gemm_bf16(
    const unsigned short* __restrict__ A,
    const unsigned short* __restrict__ Bt,
    int K,
    unsigned short* __restrict__ qb,
    unsigned short* __restrict__ kb,
    unsigned short* __restrict__ vt,
    float* __restrict__ outp,
    const float* __restrict__ bias)
{
  __shared__ short As[128][40];  // stride 80B: uniform bank spread for b128
  __shared__ short Bs[128][40];
  const int m0 = blockIdx.x * 128, n0 = blockIdx.y * 128;
  const int t = threadIdx.x;
  const int lane = t & 63, w = t >> 6;
  const int l15 = lane & 15, g = lane >> 4;
  const int wm = w >> 1, wn = w & 1;
  const int ar = t >> 2, ac = (t & 3) * 8;   // 512 chunks of 8 bf16, 2/thread

  f32x4 zv = {0.f, 0.f, 0.f, 0.f};
  f32x4 acc[4][4];
  #pragma unroll
  for (int i = 0; i < 4; ++i)
    #pragma unroll
    for (int j = 0; j < 4; ++j) acc[i][j] = zv;

  const size_t szK = (size_t)K;
  for (int k0 = 0; k0 < K; k0 += 32) {
    int4 a0 = *(const int4*)(A  + (size_t)(m0 + ar)      * szK + k0 + ac);
    int4 a1 = *(const int4*)(A  + (size_t)(m0 + ar + 64) * szK + k0 + ac);
    int4 b0 = *(const int4*)(Bt + (size_t)(n0 + ar)      * szK + k0 + ac);
    int4 b1 = *(const int4*)(Bt + (size_t)(n0 + ar + 64) * szK + k0 + ac);
    __syncthreads();
    *(int4*)&As[ar][ac]      = a0;
    *(int4*)&As[ar + 64][ac] = a1;
    *(int4*)&Bs[ar][ac]      = b0;
    *(int4*)&Bs[ar + 64][ac] = b1;
    __syncthreads();
    bf16x8 af[4], bfr[4];
    #pragma unroll
    for (int i = 0; i < 4; ++i) af[i]  = *(const bf16x8*)&As[wm*64 + i*16 + l15][g*8];
    #pragma unroll
    for (int i = 0; i < 4; ++i) bfr[i] = *(const bf16x8*)&Bs[wn*64 + i*16 + l15][g*8];
    #pragma unroll
    for (int i = 0; i < 4; ++i)
      #pragma unroll
      for (int j = 0; j < 4; ++j)
        acc[i][j] = __builtin_amdgcn_mfma_f32_16x16x32_bf16(af[i], bfr[j], acc[i][j], 0, 0, 0);
  }

  const int mbase = m0 + wm * 64, nbase = n0 + wn * 64;
  if (QKV) {
    #pragma unroll
    for (int i = 0; i < 4; ++i) {
      #pragma unroll
      for (int j = 0; j < 4; ++j) {
        int n = nbase + j * 16 + l15;
        int which = n / DIM;
        int jr = n - which * DIM;
        int head = jr >> 6, dd = jr & 63;
        size_t bhbase;
        #pragma unroll
        for (int r = 0; r < 4; ++r) {
          int m = mbase + i * 16 + g * 4 + r;
          int bb = m >> 10, nn = m & 1023;
          unsigned short val = f2bf(acc[i][j][r]);
          size_t bh = (size_t)bb * NH + head;
          if (which == 0)      qb[(bh * SEQ + nn) * HD + dd] = val;
          else if (which == 1) kb[(bh * SEQ + nn) * HD + dd] = val;
          else                 vt[(bh * HD + dd) * SEQ + nn] = val;
        }
        (void)bhbase;
      }
    }
  } else {
    #pragma unroll
    for (int i = 0; i < 4; ++i)
      #pragma unroll
      for (int j = 0; j < 4; ++j) {
        int n = nbase + j * 16 + l15;
        float bv = bias[n];
        #pragma unroll
        for (int r = 0; r < 4; ++r) {
          int m = mbase + i * 16 + g * 4 + r;
          outp[(size_t)m * DIM + n] = acc[i][j][r] + bv;
        }
      }
  }
}

// ---------- flash attention: 1 block = 1 (b,h) x 128 q-rows, 4 waves x 32 rows ----------
__global__ __launch_bounds__(256) void attn_kernel(
    const unsigned short* __restrict__ qb,
    const unsigned short* __restrict__ kb,
    const unsigned short* __restrict__ vt,
    unsigned short* __restrict__ ao)
{
  __shared__ short Ks[64][72];      // [kv][dd], 144B stride
  __shared__ short Vs[64][72];      // [dd][kv]
  __shared__ short Ps[4][32][72];   // per-wave P
  const int bid = blockIdx.x;
  const int qt = (bid & 7) * 128;
  const int bh = bid >> 3;
  const int t = threadIdx.x, lane = t & 63, w = t >> 6;
  const int l15 = lane & 15, g = lane >> 4;
  const unsigned short* Qp = qb + (size_t)bh * SEQ * HD;
  const unsigned short* Kp = kb + (size_t)bh * SEQ * HD;
  const unsigned short* Vp = vt + (size_t)bh * HD * SEQ;
  const int q0 = qt + w * 32;

  bf16x8 aq[2][2];
  #pragma unroll
  for (int fm = 0; fm < 2; ++fm)
    #pragma unroll
    for (int kk = 0; kk < 2; ++kk)
      aq[fm][kk] = *(const bf16x8*)(Qp + (size_t)(q0 + fm*16 + l15) * HD + kk*32 + g*8);

  f32x4 zv = {0.f, 0.f, 0.f, 0.f};
  f32x4 accO[2][4];
  float mrow[2][4], lrow[2][4];
  #pragma unroll
  for (int fm = 0; fm < 2; ++fm) {
    #pragma unroll
    for (int j = 0; j < 4; ++j) accO[fm][j] = zv;
    #pragma unroll
    for (int r = 0; r < 4; ++r) { mrow[fm][r] = -INFINITY; lrow[fm][r] = 0.f; }
  }

  const int sr = t >> 3, sc = (t & 7) * 8;  // staging: 64 rows x 8 chunks
  for (int kt = 0; kt < SEQ; kt += 64) {
    __syncthreads();   // previous tile's LDS reads complete
    *(int4*)&Ks[sr][sc]      = *(const int4*)(Kp + (size_t)(kt + sr)      * HD + sc);
    *(int4*)&Ks[sr + 32][sc] = *(const int4*)(Kp + (size_t)(kt + sr + 32) * HD + sc);
    *(int4*)&Vs[sr][sc]      = *(const int4*)(Vp + (size_t)sr        * SEQ + kt + sc);
    *(int4*)&Vs[sr + 32][sc] = *(const int4*)(Vp + (size_t)(sr + 32) * SEQ + kt + sc);
    __syncthreads();

    // S = Q K^T  (A=Q rows, B=K^T: Ks[kv][dd] read as B[k=dd][n=kv])
    f32x4 s[2][4];
    #pragma unroll
    for (int fm = 0; fm < 2; ++fm)
      #pragma unroll
      for (int fn = 0; fn < 4; ++fn) s[fm][fn] = zv;
    #pragma unroll
    for (int fn = 0; fn < 4; ++fn)
      #pragma unroll
      for (int kk = 0; kk < 2; ++kk) {
        bf16x8 bk = *(const bf16x8*)&Ks[fn*16 + l15][kk*32 + g*8];
        s[0][fn] = __builtin_amdgcn_mfma_f32_16x16x32_bf16(aq[0][kk], bk, s[0][fn], 0, 0, 0);
        s[1][fn] = __builtin_amdgcn_mfma_f32_16x16x32_bf16(aq[1][kk], bk, s[1][fn], 0, 0, 0);
      }

    // online softmax (rows live across lanes' 16-col groups)
    #pragma unroll
    for (int fm = 0; fm < 2; ++fm)
      #pragma unroll
      for (int r = 0; r < 4; ++r) {
        float s0 = s[fm][0][r] * 0.125f, s1 = s[fm][1][r] * 0.125f;
        float s2 = s[fm][2][r] * 0.125f, s3 = s[fm][3][r] * 0.125f;
        float mx = fmaxf(fmaxf(s0, s1), fmaxf(s2, s3));
        mx = fmaxf(mx, __shfl_xor(mx, 1, 64));
        mx = fmaxf(mx, __shfl_xor(mx, 2, 64));
        mx = fmaxf(mx, __shfl_xor(mx, 4, 64));
        mx = fmaxf(mx, __shfl_xor(mx, 8, 64));
        float mold = mrow[fm][r];
        float mnew = fmaxf(mold, mx);
        float al = __expf(mold - mnew);
        mrow[fm][r] = mnew;
        float p0 = __expf(s0 - mnew), p1 = __expf(s1 - mnew);
        float p2 = __expf(s2 - mnew), p3 = __expf(s3 - mnew);
        float rs = (p0 + p1) + (p2 + p3);
        rs += __shfl_xor(rs, 1, 64);
        rs += __shfl_xor(rs, 2, 64);
        rs += __shfl_xor(rs, 4, 64);
        rs += __shfl_xor(rs, 8, 64);
        lrow[fm][r] = lrow[fm][r] * al + rs;
        #pragma unroll
        for (int fn = 0; fn < 4; ++fn) accO[fm][fn][r] *= al;
        int prow = fm * 16 + g * 4 + r;
        Ps[w][prow][0*16 + l15] = (short)f2bf(p0);
        Ps[w][prow][1*16 + l15] = (short)f2bf(p1);
        Ps[w][prow][2*16 + l15] = (short)f2bf(p2);
        Ps[w][prow][3*16 + l15] = (short)f2bf(p3);
      }
    __syncthreads();   // P visible (and uniform re-convergence)

    // O += P V   (A=P rows, B=V: Vs[dd][kv] read as B[k=kv][n=dd])
    bf16x8 ap[2][2];
    #pragma unroll
    for (int fm = 0; fm < 2; ++fm)
      #pragma unroll
      for (int kk = 0; kk < 2; ++kk)
        ap[fm][kk] = *(const bf16x8*)&Ps[w][fm*16 + l15][kk*32 + g*8];
    #pragma unroll
    for (int fn = 0; fn < 4; ++fn)
      #pragma unroll
      for (int kk = 0; kk < 2; ++kk) {
        bf16x8 bv = *(const bf16x8*)&Vs[fn*16 + l15][kk*32 + g*8];
        accO[0][fn] = __builtin_amdgcn_mfma_f32_16x16x32_bf16(ap[0][kk], bv, accO[0][fn], 0, 0, 0);
        accO[1][fn] = __builtin_amdgcn_mfma_f32_16x16x32_bf16(ap[1][kk], bv, accO[1][fn], 0, 0, 0);
      }
  }

  const int bb = bh / NH, hh = bh - bb * NH;
  #pragma unroll
  for (int fm = 0; fm < 2; ++fm)
    #pragma unroll
    for (int r = 0; r < 4; ++r) {
      float inv = 1.f / lrow[fm][r];
      int qq = q0 + fm * 16 + g * 4 + r;
      #pragma unroll
      for (int fn = 0; fn < 4; ++fn) {
        int dd = fn * 16 + l15;
        ao[((size_t)(bb * SEQ + qq)) * DIM + hh * HD + dd] = f2bf(accO[fm][fn][r] * inv);
      }
    }
}

extern "C" void kernel_launch(void* const* d_in, const int* in_sizes, int n_in,
                              void* d_out, int out_size, void* d_ws, size_t ws_size,
                              hipStream_t stream) {
  const float* x     = (const float*)d_in[0];
  const float* Wqkv  = (const float*)d_in[1];
  const float* Wproj = (const float*)d_in[2];
  const float* bproj = (const float*)d_in[3];
  float* out = (float*)d_out;

  unsigned short* ws = (unsigned short*)d_ws;
  const size_t NX = (size_t)NUM_B * SEQ * DIM;          // 6,291,456
  unsigned short* x_bf    = ws;
  unsigned short* Wqkv_t  = x_bf + NX;                  // [2304][768]
  unsigned short* Wproj_t = Wqkv_t + (size_t)3 * DIM * DIM;  // [768][768]
  unsigned short* qbuf    = Wproj_t + (size_t)DIM * DIM;     // [B,h,N,d]
  unsigned short* kbuf    = qbuf + NX;                  // [B,h,N,d]
  unsigned short* vtb     = kbuf + NX;                  // [B,h,d,N]
  unsigned short* attb    = vtb + NX;                   // [B*N][768]

  cvt_kernel<<<dim3((unsigned)(NX / 4 / 256)), 256, 0, stream>>>(x, x_bf, (int)NX);
  tcvt_kernel<<<dim3(3 * DIM / 32, DIM / 32), dim3(32, 8), 0, stream>>>(Wqkv, Wqkv_t, DIM, 3 * DIM);
  tcvt_kernel<<<dim3(DIM / 32, DIM / 32), dim3(32, 8), 0, stream>>>(Wproj, Wproj_t, DIM, DIM);

  gemm_bf16<true><<<dim3(64, 18), 256, 0, stream>>>(
      x_bf, Wqkv_t, DIM, qbuf, kbuf, vtb, nullptr, nullptr);

  attn_kernel<<<dim3(NUM_B * NH * (SEQ / 128)), 256, 0, stream>>>(qbuf, kbuf, vtb, attb);

  gemm_bf16<false><<<dim3(64, 6), 256, 0, stream>>>(
      attb, Wproj_t, DIM, nullptr, nullptr, nullptr, out, bproj);
}